// Round 1
// baseline (197.243 us; speedup 1.0000x reference)
//
#include <hip/hip_runtime.h>
#include <hip/hip_cooperative_groups.h>

namespace cg = cooperative_groups;

// KPConv simple block: grid + block-union MFMA KPConv + BN + LeakyReLU
// B=8, N=4096 -> M=32768; C_IN=64, C_OUT=128, K=15 kernel pts.
//
// R13 = R12 conv core (unchanged, verified) with dispatch fusion:
//  (1) kpre_coop: memset+k0a+k0b+k0c fused via 3x grid.sync (4 disp -> 1)
//  (2) k2_coop: persistent 1024 blocks x 2 tiles, acc held in registers
//      across grid.sync, BN finalize fused in-register (k2+k4 -> 1 disp,
//      out written once: -32 MB HBM)
//  (3) runtime-guarded fallback to the R12 5-dispatch path if cooperative
//      launch is unavailable/fails.

#define NB     8
#define NPTS   4096
#define M_TOT  32768
#define CIN    64
#define COUT   128
#define NKP    15
#define NCELL  1728            // 12^3
#define UCAP   512             // union cap (mean ~70)
#define R2EFF  (0.082f * 0.082f)
#define KP_INV 25.0f           // 1 / KP_EXTENT(0.04)
#define NEG_SLOPE 0.2f
#define KCP    1024            // kc' = c*16+k (k=15 slots zero)
#define WFPAD  1032            // wf row stride (shorts), 16B-aligned
#define SP     40              // S/FT row stride (shorts), 80B

typedef float f32x4_t __attribute__((ext_vector_type(4)));
typedef short bf16x8_t __attribute__((ext_vector_type(8)));

__device__ __forceinline__ unsigned short f2bf(float f) {
  union { float f; unsigned u; } v; v.f = f;
  unsigned r = v.u + 0x7FFF + ((v.u >> 16) & 1);   // RNE
  return (unsigned short)(r >> 16);
}
__device__ __forceinline__ int cell_of(float x, float y, float z) {
  int cx = (int)(x * 12.f); cx = cx > 11 ? 11 : cx;
  int cy = (int)(y * 12.f); cy = cy > 11 ? 11 : cy;
  int cz = (int)(z * 12.f); cz = cz > 11 ? 11 : cz;
  return (cz * 12 + cy) * 12 + cx;
}

// ---------------------------------------------------------------------------
// kpre_coop: zero -> hist -> (scan | W->Wt) -> scatter, one cooperative kernel
// grid = 128 blocks x 256 threads (= 32768 = one thread per point)
// ---------------------------------------------------------------------------
__global__ __launch_bounds__(256) void kpre_coop(
    const float* __restrict__ xyz, const float* __restrict__ feats,
    const float* __restrict__ W,
    int* __restrict__ cellcnt,      // base of contiguous zero region
    int* __restrict__ cellfill, int* __restrict__ cellstart,
    int* __restrict__ qorder, float4* __restrict__ xyzs,
    unsigned short* __restrict__ fsorted, unsigned short* __restrict__ Wt)
{
  cg::grid_group grid = cg::this_grid();
  __shared__ int ps[256];
  const int tid = threadIdx.x;
  const int idx = blockIdx.x * 256 + tid;

  // ---- phase Z: zero cellcnt+cellfill+psum+psumsq (27904 contiguous ints)
  if (idx < 27904) cellcnt[idx] = 0;
  grid.sync();

  // ---- phase A: per-cell histogram
  {
    const float x = xyz[idx * 3], y = xyz[idx * 3 + 1], z = xyz[idx * 3 + 2];
    const int b = idx >> 12;
    atomicAdd(&cellcnt[b * NCELL + cell_of(x, y, z)], 1);
  }
  grid.sync();

  // ---- phase B: blocks 0..7 = per-batch exclusive scan; 8..39 = W -> Wt
  if (blockIdx.x >= 8 && blockIdx.x < 40) {
    const int i2 = (blockIdx.x - 8) * 256 + tid;           // 8192
    const int d = i2 & 127, c = i2 >> 7;                   // c 0..63
    union { unsigned short s[16]; uint4 v[2]; } u;
    #pragma unroll
    for (int k = 0; k < NKP; k++)
      u.s[k] = f2bf(W[(size_t)k * (CIN * COUT) + c * COUT + d]);
    u.s[15] = 0;
    uint4* dst = (uint4*)&Wt[(size_t)d * KCP + c * 16];
    dst[0] = u.v[0]; dst[1] = u.v[1];
  } else if (blockIdx.x < 8) {
    const int b = blockIdx.x, t = tid;
    int local[7], s = 0;
    #pragma unroll
    for (int i = 0; i < 7; i++) {
      const int cid = t * 7 + i;
      const int c = (cid < NCELL) ? cellcnt[b * NCELL + cid] : 0;
      local[i] = c; s += c;
    }
    ps[t] = s; __syncthreads();
    for (int off = 1; off < 256; off <<= 1) {
      int v = (t >= off) ? ps[t - off] : 0;
      __syncthreads();
      ps[t] += v;
      __syncthreads();
    }
    int run = ps[t] - s;
    #pragma unroll
    for (int i = 0; i < 7; i++) {
      const int cid = t * 7 + i;
      if (cid < NCELL) { cellstart[b * 1729 + cid] = run; run += local[i]; }
    }
    if (t == 255) cellstart[b * 1729 + NCELL] = ps[255];
  }
  grid.sync();

  // ---- phase C: counting-sort scatter -> qorder + sorted xyz + bf16 feats
  {
    const float x = xyz[idx * 3], y = xyz[idx * 3 + 1], z = xyz[idx * 3 + 2];
    const int b = idx >> 12;
    const int cid = cell_of(x, y, z);
    const int slot = atomicAdd(&cellfill[b * NCELL + cid], 1);
    const int pos = b * NPTS + cellstart[b * 1729 + cid] + slot;
    qorder[pos] = idx;
    xyzs[pos] = make_float4(x, y, z, 0.f);
    const float* src = &feats[(size_t)idx * CIN];
    uint4* dst = (uint4*)&fsorted[(size_t)pos * CIN];
    #pragma unroll
    for (int g = 0; g < 8; g++) {
      float4 a = *(const float4*)(src + g * 8);
      float4 c = *(const float4*)(src + g * 8 + 4);
      union { unsigned short s[8]; uint4 v; } u;
      u.s[0] = f2bf(a.x); u.s[1] = f2bf(a.y); u.s[2] = f2bf(a.z); u.s[3] = f2bf(a.w);
      u.s[4] = f2bf(c.x); u.s[5] = f2bf(c.y); u.s[6] = f2bf(c.z); u.s[7] = f2bf(c.w);
      dst[g] = u.v;
    }
  }
}

// ---------------------------------------------------------------------------
// Fallback preprocessing kernels (R12, unchanged)
// ---------------------------------------------------------------------------
__global__ __launch_bounds__(256) void k0a_hist(
    const float* __restrict__ xyz, int* __restrict__ cellcnt)
{
  const int pt = blockIdx.x * 256 + threadIdx.x;
  const float x = xyz[pt * 3], y = xyz[pt * 3 + 1], z = xyz[pt * 3 + 2];
  const int b = pt >> 12;
  atomicAdd(&cellcnt[b * NCELL + cell_of(x, y, z)], 1);
}

__global__ __launch_bounds__(256) void k0b_scan_kW(
    const int* __restrict__ cellcnt, int* __restrict__ cellstart,
    const float* __restrict__ W, unsigned short* __restrict__ Wt)
{
  if (blockIdx.x >= 8) {
    const int idx = (blockIdx.x - 8) * 256 + threadIdx.x;  // 8192
    const int d = idx & 127, c = idx >> 7;                 // c 0..63
    union { unsigned short s[16]; uint4 v[2]; } u;
    #pragma unroll
    for (int k = 0; k < NKP; k++)
      u.s[k] = f2bf(W[(size_t)k * (CIN * COUT) + c * COUT + d]);
    u.s[15] = 0;
    uint4* dst = (uint4*)&Wt[(size_t)d * KCP + c * 16];
    dst[0] = u.v[0]; dst[1] = u.v[1];
    return;
  }
  __shared__ int ps[256];
  const int b = blockIdx.x, t = threadIdx.x;
  int local[7], s = 0;
  #pragma unroll
  for (int i = 0; i < 7; i++) {
    const int cid = t * 7 + i;
    const int c = (cid < NCELL) ? cellcnt[b * NCELL + cid] : 0;
    local[i] = c; s += c;
  }
  ps[t] = s; __syncthreads();
  for (int off = 1; off < 256; off <<= 1) {
    int v = (t >= off) ? ps[t - off] : 0;
    __syncthreads();
    ps[t] += v;
    __syncthreads();
  }
  int run = ps[t] - s;
  #pragma unroll
  for (int i = 0; i < 7; i++) {
    const int cid = t * 7 + i;
    if (cid < NCELL) { cellstart[b * 1729 + cid] = run; run += local[i]; }
  }
  if (t == 255) cellstart[b * 1729 + NCELL] = ps[255];
}

__global__ __launch_bounds__(256) void k0c_scatter(
    const float* __restrict__ xyz, const float* __restrict__ feats,
    const int* __restrict__ cellstart, int* __restrict__ cellfill,
    int* __restrict__ qorder, float4* __restrict__ xyzs,
    unsigned short* __restrict__ fsorted)
{
  const int pt = blockIdx.x * 256 + threadIdx.x;
  const float x = xyz[pt * 3], y = xyz[pt * 3 + 1], z = xyz[pt * 3 + 2];
  const int b = pt >> 12;
  const int cid = cell_of(x, y, z);
  const int slot = atomicAdd(&cellfill[b * NCELL + cid], 1);
  const int pos = b * NPTS + cellstart[b * 1729 + cid] + slot;
  qorder[pos] = pt;
  xyzs[pos] = make_float4(x, y, z, 0.f);
  const float* src = &feats[(size_t)pt * CIN];
  uint4* dst = (uint4*)&fsorted[(size_t)pos * CIN];
  #pragma unroll
  for (int g = 0; g < 8; g++) {
    float4 a = *(const float4*)(src + g * 8);
    float4 c = *(const float4*)(src + g * 8 + 4);
    union { unsigned short s[8]; uint4 v; } u;
    u.s[0] = f2bf(a.x); u.s[1] = f2bf(a.y); u.s[2] = f2bf(a.z); u.s[3] = f2bf(a.w);
    u.s[4] = f2bf(c.x); u.s[5] = f2bf(c.y); u.s[6] = f2bf(c.z); u.s[7] = f2bf(c.w);
    dst[g] = u.v;
  }
}

// ---------------------------------------------------------------------------
// conv_tile: the R12 k2 core for ONE 16-query tile (bt). Produces the two
// per-thread accumulators (acc2) and the 4 output row indices (rows).
// Identical phase structure to R12; leading __syncthreads protects the
// phase-aliased LDS from the previous tile's readers.
// ---------------------------------------------------------------------------
__device__ __forceinline__ void conv_tile(
    const int bt,
    const float4* __restrict__ xyzs, const unsigned short* __restrict__ fsorted,
    const int* __restrict__ cellstart, const int* __restrict__ qorder,
    const unsigned short* __restrict__ Wt,
    float* __restrict__ psum, float* __restrict__ psumsq,
    char* smraw, float4* qd, int* qm, float (*kp)[4],
    int* Tsh_p, int* ucnt_p,
    f32x4_t acc2[2], int rows[4])
{
  float4*         Pu   = (float4*)smraw;
  unsigned short* cpos = (unsigned short*)(smraw + 8192);
  short (*S)[SP]       = (short(*)[SP])(smraw + 8192);
  short (*FT)[SP]      = (short(*)[SP])(smraw + 28672);
  short (*wf)[WFPAD]   = (short(*)[WFPAD])smraw;

  const int tid = threadIdx.x;
  const int w   = tid >> 6;
  const int L   = tid & 63;
  const int m0  = bt * 16;
  const int b   = m0 >> 12;

  __syncthreads();   // previous tile's LDS readers done; safe to overwrite

  // ---- wave-0 prologue: bbox -> row ranges -> pfx (shfl scan) -> cpos ----
  if (tid < 64) {
    int cxm = 12, cym = 12, czm = 12, cxM = -1, cyM = -1, czM = -1;
    if (tid < 16) {
      const float4 Q = xyzs[m0 + tid];
      qd[tid] = Q;
      qm[tid] = qorder[m0 + tid];
      int a = (int)(Q.x * 12.f); a = a > 11 ? 11 : a;
      int c = (int)(Q.y * 12.f); c = c > 11 ? 11 : c;
      int d = (int)(Q.z * 12.f); d = d > 11 ? 11 : d;
      cxm = cxM = a; cym = cyM = c; czm = czM = d;
    }
    #pragma unroll
    for (int off = 8; off >= 1; off >>= 1) {
      int v;
      v = __shfl_xor(cxm, off); cxm = v < cxm ? v : cxm;
      v = __shfl_xor(cxM, off); cxM = v > cxM ? v : cxM;
      v = __shfl_xor(cym, off); cym = v < cym ? v : cym;
      v = __shfl_xor(cyM, off); cyM = v > cyM ? v : cyM;
      v = __shfl_xor(czm, off); czm = v < czm ? v : czm;
      v = __shfl_xor(czM, off); czM = v > czM ? v : czM;
    }
    cxm = __shfl(cxm, 0); cxM = __shfl(cxM, 0);
    cym = __shfl(cym, 0); cyM = __shfl(cyM, 0);
    czm = __shfl(czm, 0); czM = __shfl(czM, 0);

    const int x0 = cxm > 0 ? cxm - 1 : 0, x1 = cxM < 11 ? cxM + 1 : 11;
    const int y0 = cym > 0 ? cym - 1 : 0, y1 = cyM < 11 ? cyM + 1 : 11;
    const int z0 = czm > 0 ? czm - 1 : 0, z1 = czM < 11 ? czM + 1 : 11;
    const int yspan = y1 - y0 + 1;
    int nr = yspan * (z1 - z0 + 1);
    nr = nr > 64 ? 64 : nr;

    int rs = 0, len = 0;
    if (tid < nr) {
      const int zz = z0 + tid / yspan, yy = y0 + tid % yspan;
      const int base = b * 1729 + (zz * 12 + yy) * 12;
      rs  = cellstart[base + x0];
      len = cellstart[base + x1 + 1] - rs;
    }
    int incl = len;
    #pragma unroll
    for (int off = 1; off < 64; off <<= 1) {
      const int v = __shfl_up(incl, off);
      if (tid >= off) incl += v;
    }
    const int excl = incl - len;
    for (int i = 0; i < len; i++) cpos[excl + i] = (unsigned short)(rs + i);
    if (tid == 63) *Tsh_p = incl;
    if (tid == 62) *ucnt_p = 0;
  }
  __syncthreads();
  const int T = *Tsh_p;

  // ---- union search: any-hit over 16 queries, branch-free test ----
  for (int tb = 0; tb < T; tb += 256) {
    const int t = tb + tid;
    if (t < T) {
      const int pos = (int)cpos[t];
      const float4 P = xyzs[b * NPTS + pos];
      float best = 1e9f;
      #pragma unroll
      for (int i = 0; i < 16; i++) {
        const float4 Q = qd[i];
        const float dx = P.x - Q.x, dy = P.y - Q.y, dz = P.z - Q.z;
        const float d2 = dx * dx + dy * dy + dz * dz;
        best = d2 < best ? d2 : best;
      }
      if (best <= R2EFF) {
        const int slot = atomicAdd(ucnt_p, 1);
        if (slot < UCAP)
          Pu[slot] = make_float4(P.x, P.y, P.z, __int_as_float(pos));
      }
    }
  }
  __syncthreads();
  int U = *ucnt_p; U = U > UCAP ? UCAP : U;

  // ---- stage-1: chunked MFMA over the union ----
  const int ln = L & 15;
  const int kh = L >> 4;

  f32x4_t acc[16];
  #pragma unroll
  for (int mt = 0; mt < 16; mt++) acc[mt] = (f32x4_t){0.f, 0.f, 0.f, 0.f};

  for (int ub = 0; ub < U; ub += 32) {
    // FT[c][i]: sorted bf16 rows (L2-hot, spatially local)
    {
      const int c  = tid & 63;
      const int i0 = tid >> 6;
      #pragma unroll
      for (int ii = 0; ii < 8; ii++) {
        const int i = ii * 4 + i0;
        const int u = ub + i;
        short v = 0;
        if (u < U) {
          const int pos = __float_as_int(Pu[u].w);
          v = (short)fsorted[(size_t)(b * NPTS + pos) * CIN + c];
        }
        FT[c][i] = v;
      }
    }
    // S[q*16+k][n]: sparse influence eval (zeros outside radius / pad)
    #pragma unroll
    for (int rep = 0; rep < 2; rep++) {
      const int p = rep * 256 + tid;     // 512 = 16q x 32n
      const int q = p >> 5;
      const int n = p & 31;
      const int u = ub + n;
      if (u < U) {
        const float4 P = Pu[u];
        const float4 Q = qd[q];
        const float rx = P.x - Q.x, ry = P.y - Q.y, rz = P.z - Q.z;
        #pragma unroll
        for (int k = 0; k < NKP; k++) {
          const float dx = rx - kp[k][0];
          const float dy = ry - kp[k][1];
          const float dz = rz - kp[k][2];
          const float wv =
              fmaxf(1.f - sqrtf(dx * dx + dy * dy + dz * dz) * KP_INV, 0.f);
          S[q * 16 + k][n] = (short)f2bf(wv);
        }
        S[q * 16 + 15][n] = 0;
      } else {
        #pragma unroll
        for (int k = 0; k < 16; k++) S[q * 16 + k][n] = 0;
      }
    }
    __syncthreads();

    // MFMA: wave w = c-tile w; 16 query m-tiles
    bf16x8_t bb = *(const bf16x8_t*)&FT[w * 16 + ln][kh * 8];
    #pragma unroll
    for (int mt = 0; mt < 16; mt++) {
      bf16x8_t aa = *(const bf16x8_t*)&S[mt * 16 + ln][kh * 8];
      acc[mt] = __builtin_amdgcn_mfma_f32_16x16x32_bf16(aa, bb, acc[mt],
                                                        0, 0, 0);
    }
    __syncthreads();
  }

  // ---- writeback: D -> wf[q][c*16+k] (aliased region; S/FT/Pu dead) ----
  #pragma unroll
  for (int mt = 0; mt < 16; mt++) {
    union { unsigned short s[4]; unsigned long long d; } u;
    #pragma unroll
    for (int j = 0; j < 4; j++) u.s[j] = f2bf(acc[mt][j]);
    *(unsigned long long*)&wf[mt][(w * 16 + ln) * 16 + kh * 4] = u.d;
  }
  __syncthreads();

  // ---- stage-2: out[16][128] = wf[16][1024] @ Wt^T ----
  const int colbase = w * 32;

  acc2[0] = (f32x4_t){0.f, 0.f, 0.f, 0.f};
  acc2[1] = (f32x4_t){0.f, 0.f, 0.f, 0.f};

  const unsigned short* Bp0 = &Wt[(size_t)(colbase + ln) * KCP + kh * 8];
  const unsigned short* Bp1 = Bp0 + 16 * KCP;
  const short* Ap = &wf[ln][kh * 8];

  #pragma unroll 4
  for (int kk = 0; kk < 32; kk++) {
    const int ko = kk * 32;
    bf16x8_t b0 = *(const bf16x8_t*)(Bp0 + ko);
    bf16x8_t b1 = *(const bf16x8_t*)(Bp1 + ko);
    bf16x8_t a0 = *(const bf16x8_t*)(Ap + ko);
    acc2[0] = __builtin_amdgcn_mfma_f32_16x16x32_bf16(a0, b0, acc2[0], 0, 0, 0);
    acc2[1] = __builtin_amdgcn_mfma_f32_16x16x32_bf16(a0, b1, acc2[1], 0, 0, 0);
  }

  // BN partials: reduce 16 rows across kh via shfl, atomic into psum[128]
  float s0 = 0.f, q0 = 0.f, s1 = 0.f, q1 = 0.f;
  #pragma unroll
  for (int j = 0; j < 4; j++) {
    s0 += acc2[0][j]; q0 += acc2[0][j] * acc2[0][j];
    s1 += acc2[1][j]; q1 += acc2[1][j] * acc2[1][j];
  }
  s0 += __shfl_xor(s0, 16); s0 += __shfl_xor(s0, 32);
  q0 += __shfl_xor(q0, 16); q0 += __shfl_xor(q0, 32);
  s1 += __shfl_xor(s1, 16); s1 += __shfl_xor(s1, 32);
  q1 += __shfl_xor(q1, 16); q1 += __shfl_xor(q1, 32);
  if (kh == 0) {
    atomicAdd(&psum[colbase + ln], s0);
    atomicAdd(&psumsq[colbase + ln], q0);
    atomicAdd(&psum[colbase + 16 + ln], s1);
    atomicAdd(&psumsq[colbase + 16 + ln], q1);
  }

  // output rows (original point indices) for this thread's 4 accum rows
  #pragma unroll
  for (int j = 0; j < 4; j++) rows[j] = qm[kh * 4 + j];
}

// ---------------------------------------------------------------------------
// k2_coop: persistent 1024 blocks x 2 tiles; grid.sync; fused BN+LeakyReLU.
// 1024 blocks = 256 CU x 4 blocks/CU (LDS 34816 -> exactly co-resident).
// ---------------------------------------------------------------------------
__global__ __launch_bounds__(256, 4) void k2_coop(
    const float4* __restrict__ xyzs, const unsigned short* __restrict__ fsorted,
    const float* __restrict__ kpts, const int* __restrict__ cellstart,
    const int* __restrict__ qorder, const unsigned short* __restrict__ Wt,
    float* __restrict__ out, float* __restrict__ psum,
    float* __restrict__ psumsq, const float* __restrict__ gamma,
    const float* __restrict__ beta)
{
  __shared__ char smraw[33792] __attribute__((aligned(16)));
  __shared__ float4 qd[16];
  __shared__ int    qm[16];
  __shared__ float  kp[NKP][4];
  __shared__ int    Tsh;
  __shared__ int    ucnt;

  const int tid = threadIdx.x;
  if (tid >= 64 && tid < 64 + NKP * 3) {
    const int t2 = tid - 64;
    kp[t2 / 3][t2 - (t2 / 3) * 3] = kpts[t2];
  }

  f32x4_t aA[2], aB[2];
  int rA[4], rB[4];
  conv_tile(blockIdx.x, xyzs, fsorted, cellstart, qorder, Wt, psum, psumsq,
            smraw, qd, qm, kp, &Tsh, &ucnt, aA, rA);
  conv_tile(blockIdx.x + 1024, xyzs, fsorted, cellstart, qorder, Wt, psum,
            psumsq, smraw, qd, qm, kp, &Tsh, &ucnt, aB, rB);

  cg::this_grid().sync();

  // ---- fused BN finalize + LeakyReLU (k4 folded in) ----
  float* a_s = (float*)smraw;          // smraw dead after grid sync
  float* b_s = (float*)(smraw + 512);
  if (tid < 128) {
    const float s  = __hip_atomic_load(&psum[tid], __ATOMIC_RELAXED,
                                       __HIP_MEMORY_SCOPE_AGENT);
    const float sq = __hip_atomic_load(&psumsq[tid], __ATOMIC_RELAXED,
                                       __HIP_MEMORY_SCOPE_AGENT);
    double mu  = (double)s / (double)M_TOT;
    double var = (double)sq / (double)M_TOT - mu * mu;  // biased
    float rstd = (float)(1.0 / sqrt(var + 1e-5));
    float a = rstd * gamma[tid];
    a_s[tid] = a;
    b_s[tid] = beta[tid] - (float)mu * a;
  }
  __syncthreads();

  const int w  = tid >> 6;
  const int L  = tid & 63;
  const int ln = L & 15;
  const int colbase = w * 32;
  #pragma unroll
  for (int c = 0; c < 2; c++) {
    const int col = colbase + c * 16 + ln;
    const float a = a_s[col], bb = b_s[col];
    #pragma unroll
    for (int j = 0; j < 4; j++) {
      float yA = aA[c][j] * a + bb;
      yA = yA >= 0.f ? yA : NEG_SLOPE * yA;
      out[(size_t)rA[j] * COUT + col] = yA;
      float yB = aB[c][j] * a + bb;
      yB = yB >= 0.f ? yB : NEG_SLOPE * yB;
      out[(size_t)rB[j] * COUT + col] = yB;
    }
  }
}

// ---------------------------------------------------------------------------
// Fallback: k2_plain (one tile/block, raw store) + k4_norm (R12 path)
// ---------------------------------------------------------------------------
__global__ __launch_bounds__(256, 4) void k2_plain(
    const float4* __restrict__ xyzs, const unsigned short* __restrict__ fsorted,
    const float* __restrict__ kpts, const int* __restrict__ cellstart,
    const int* __restrict__ qorder, const unsigned short* __restrict__ Wt,
    float* __restrict__ out, float* __restrict__ psum,
    float* __restrict__ psumsq)
{
  __shared__ char smraw[33792] __attribute__((aligned(16)));
  __shared__ float4 qd[16];
  __shared__ int    qm[16];
  __shared__ float  kp[NKP][4];
  __shared__ int    Tsh;
  __shared__ int    ucnt;

  const int tid = threadIdx.x;
  if (tid >= 64 && tid < 64 + NKP * 3) {
    const int t2 = tid - 64;
    kp[t2 / 3][t2 - (t2 / 3) * 3] = kpts[t2];
  }

  f32x4_t acc2[2];
  int rows[4];
  conv_tile(blockIdx.x, xyzs, fsorted, cellstart, qorder, Wt, psum, psumsq,
            smraw, qd, qm, kp, &Tsh, &ucnt, acc2, rows);

  const int w  = tid >> 6;
  const int L  = tid & 63;
  const int ln = L & 15;
  const int colbase = w * 32;
  #pragma unroll
  for (int c = 0; c < 2; c++) {
    #pragma unroll
    for (int j = 0; j < 4; j++)
      out[(size_t)rows[j] * COUT + colbase + c * 16 + ln] = acc2[c][j];
  }
}

__global__ __launch_bounds__(256) void k4_norm(
    float* __restrict__ out, const float* __restrict__ psum,
    const float* __restrict__ psumsq, const float* __restrict__ gamma,
    const float* __restrict__ beta)
{
  __shared__ float a_s[128], b_s[128];
  if (threadIdx.x < 128) {
    const int d = threadIdx.x;
    double mu  = (double)psum[d] / (double)M_TOT;
    double var = (double)psumsq[d] / (double)M_TOT - mu * mu;  // biased
    float rstd = (float)(1.0 / sqrt(var + 1e-5));
    float a = rstd * gamma[d];
    a_s[d] = a;
    b_s[d] = beta[d] - (float)mu * a;
  }
  __syncthreads();
  const int idx = blockIdx.x * 256 + threadIdx.x;   // float4 index
  float4 v = ((const float4*)out)[idx];
  const int d0 = (idx * 4) & 127;
  float y0 = v.x * a_s[d0 + 0] + b_s[d0 + 0];
  float y1 = v.y * a_s[d0 + 1] + b_s[d0 + 1];
  float y2 = v.z * a_s[d0 + 2] + b_s[d0 + 2];
  float y3 = v.w * a_s[d0 + 3] + b_s[d0 + 3];
  v.x = y0 >= 0.f ? y0 : NEG_SLOPE * y0;
  v.y = y1 >= 0.f ? y1 : NEG_SLOPE * y1;
  v.z = y2 >= 0.f ? y2 : NEG_SLOPE * y2;
  v.w = y3 >= 0.f ? y3 : NEG_SLOPE * y3;
  ((float4*)out)[idx] = v;
}

// ---------------------------------------------------------------------------
extern "C" void kernel_launch(void* const* d_in, const int* in_sizes, int n_in,
                              void* d_out, int out_size, void* d_ws,
                              size_t ws_size, hipStream_t stream)
{
  const float* xyz   = (const float*)d_in[0];
  const float* feats = (const float*)d_in[1];
  const float* kpts  = (const float*)d_in[2];
  const float* W     = (const float*)d_in[3];
  const float* gamma = (const float*)d_in[4];
  const float* beta  = (const float*)d_in[5];
  float* out = (float*)d_out;

  char* ws = (char*)d_ws;
  int*            cellcnt   = (int*)(ws + 0);           //  55296 B ─┐
  int*            cellfill  = (int*)(ws + 55296);       //  55296 B  │ zeroed
  float*          psum      = (float*)(ws + 110592);    //    512 B  │
  float*          psumsq    = (float*)(ws + 111104);    //    512 B ─┘
  int*            cellstart = (int*)(ws + 111616);      //  55424 B
  int*            qorder    = (int*)(ws + 167040);      // 131072 B
  float4*         xyzs      = (float4*)(ws + 298112);   // 524288 B
  unsigned short* fsorted   = (unsigned short*)(ws + 822400);   // 4194304 B
  unsigned short* Wt        = (unsigned short*)(ws + 5016704);  // 262144 B

  // decide once: cooperative fused path vs R12 5-dispatch path
  static int coop_mode = -1;
  if (coop_mode < 0) {
    int dev = 0;
    (void)hipGetDevice(&dev);
    int coop = 0;
    (void)hipDeviceGetAttribute(&coop, hipDeviceAttributeCooperativeLaunch, dev);
    hipDeviceProp_t prop;
    int ncu = 0;
    if (hipGetDeviceProperties(&prop, dev) == hipSuccess)
      ncu = prop.multiProcessorCount;
    int occ2 = 0, occp = 0;
    (void)hipOccupancyMaxActiveBlocksPerMultiprocessor(
        &occ2, (const void*)k2_coop, 256, 0);
    (void)hipOccupancyMaxActiveBlocksPerMultiprocessor(
        &occp, (const void*)kpre_coop, 256, 0);
    coop_mode = (coop && ncu > 0 && occ2 * ncu >= 1024 && occp * ncu >= 128)
                    ? 1 : 0;
  }

  if (coop_mode == 1) {
    void* pre_args[] = {(void*)&xyz, (void*)&feats, (void*)&W,
                        (void*)&cellcnt, (void*)&cellfill, (void*)&cellstart,
                        (void*)&qorder, (void*)&xyzs, (void*)&fsorted,
                        (void*)&Wt};
    hipError_t e1 = hipLaunchCooperativeKernel(
        (const void*)kpre_coop, dim3(128), dim3(256), pre_args, 0, stream);
    if (e1 == hipSuccess) {
      void* k2_args[] = {(void*)&xyzs, (void*)&fsorted, (void*)&kpts,
                         (void*)&cellstart, (void*)&qorder, (void*)&Wt,
                         (void*)&out, (void*)&psum, (void*)&psumsq,
                         (void*)&gamma, (void*)&beta};
      hipError_t e2 = hipLaunchCooperativeKernel(
          (const void*)k2_coop, dim3(1024), dim3(256), k2_args, 0, stream);
      if (e2 == hipSuccess) return;
    }
    // cooperative launch failed (e.g. capture unsupported) -> permanent
    // fallback; clear error and re-issue full classic pipeline.
    (void)hipGetLastError();
    coop_mode = 0;
  }

  hipMemsetAsync(ws, 0, 111616, stream);
  k0a_hist   <<< 128, 256, 0, stream>>>(xyz, cellcnt);
  k0b_scan_kW<<<  40, 256, 0, stream>>>(cellcnt, cellstart, W, Wt);
  k0c_scatter<<< 128, 256, 0, stream>>>(xyz, feats, cellstart, cellfill,
                                        qorder, xyzs, fsorted);
  k2_plain   <<<2048, 256, 0, stream>>>(xyzs, fsorted, kpts, cellstart,
                                        qorder, Wt, out, psum, psumsq);
  k4_norm    <<<(out_size / 4) / 256, 256, 0, stream>>>(out, psum, psumsq,
                                                        gamma, beta);
}

// Round 2
// 195.924 us; speedup vs baseline: 1.0067x; 1.0067x over previous
//
#include <hip/hip_runtime.h>

// KPConv simple block: grid + block-union MFMA KPConv + BN + LeakyReLU
// B=8, N=4096 -> M=32768; C_IN=64, C_OUT=128, K=15 kernel pts.
//
// Exact simplification: influence w = max(1 - d/0.04, 0) with ||kp||<=0.042
// => candidates with ||rel|| >= 0.082 contribute 0 to every kernel point;
// the within-0.082 set == reference top-k result.
//
// R14 = R12 classic 5-dispatch pipeline with k2 rebuilt for occupancy:
//  (1) LDS 34816 -> 32768 B => 5 blocks/CU (was 4): S split into two
//      8-query half-passes ([128][40] instead of [256][40]), wf k-major
//      960-wide (k=15 slot dropped) XOR-swizzled, UCAP 512->400.
//  (2) S-eval diet: d^2 = |r|^2 - 2 r.kp + |kp|^2 with pre-scaled kp
//      (saves 2 VALU/k), raw v_sqrt_f32, 2-op half-up bf16 rounding.
//  (3) stage-2 K = 960 (30 MFMA steps, was 32); Wt in matching k-major.
//  R13 coop fusion removed: measured neutral (launches already pipeline).

#define NB     8
#define NPTS   4096
#define M_TOT  32768
#define CIN    64
#define COUT   128
#define NKP    15
#define NCELL  1728            // 12^3
#define UCAP   400             // union cap (mean ~70)
#define R2EFF  (0.082f * 0.082f)
#define KP_INV 25.0f           // 1 / KP_EXTENT(0.04)
#define NEG_SLOPE 0.2f
#define KCP    960             // kc' = k*64+c, k-major, k=15 dropped
#define WFROW  1920            // wf row stride bytes (960 bf16)
#define SP     40              // S/FT row stride (shorts), 80B

typedef float f32x4_t __attribute__((ext_vector_type(4)));
typedef short bf16x8_t __attribute__((ext_vector_type(8)));

__device__ __forceinline__ unsigned short f2bf(float f) {
  union { float f; unsigned u; } v; v.f = f;
  unsigned r = v.u + 0x7FFF + ((v.u >> 16) & 1);   // RNE
  return (unsigned short)(r >> 16);
}
// half-up rounding: same 0.5 ulp max error as RNE, 2 VALU ops
__device__ __forceinline__ unsigned short f2bf_fast(float f) {
  union { float f; unsigned u; } v; v.f = f;
  return (unsigned short)((v.u + 0x8000u) >> 16);
}
__device__ __forceinline__ int cell_of(float x, float y, float z) {
  int cx = (int)(x * 12.f); cx = cx > 11 ? 11 : cx;
  int cy = (int)(y * 12.f); cy = cy > 11 ? 11 : cy;
  int cz = (int)(z * 12.f); cz = cz > 11 ? 11 : cz;
  return (cz * 12 + cy) * 12 + cx;
}

// ---------------------------------------------------------------------------
// K0a: per-cell histogram
// ---------------------------------------------------------------------------
__global__ __launch_bounds__(256) void k0a_hist(
    const float* __restrict__ xyz, int* __restrict__ cellcnt)
{
  const int pt = blockIdx.x * 256 + threadIdx.x;
  const float x = xyz[pt * 3], y = xyz[pt * 3 + 1], z = xyz[pt * 3 + 2];
  const int b = pt >> 12;
  atomicAdd(&cellcnt[b * NCELL + cell_of(x, y, z)], 1);
}

// ---------------------------------------------------------------------------
// K0b: blocks 0..7 = per-batch exclusive scan; blocks 8..39 = W -> Wt
// Wt[d][k*64+c] bf16, k-major, k=15 dropped (its S rows are zero anyway).
// ---------------------------------------------------------------------------
__global__ __launch_bounds__(256) void k0b_scan_kW(
    const int* __restrict__ cellcnt, int* __restrict__ cellstart,
    const float* __restrict__ W, unsigned short* __restrict__ Wt)
{
  if (blockIdx.x >= 8) {
    const int idx = (blockIdx.x - 8) * 256 + threadIdx.x;  // 8192
    const int c = idx & 63, d = idx >> 6;                  // d 0..127
    #pragma unroll
    for (int k = 0; k < NKP; k++)
      Wt[(size_t)d * KCP + k * 64 + c] =
          f2bf(W[(size_t)k * (CIN * COUT) + c * COUT + d]);
    return;
  }
  __shared__ int ps[256];
  const int b = blockIdx.x, t = threadIdx.x;
  int local[7], s = 0;
  #pragma unroll
  for (int i = 0; i < 7; i++) {
    const int cid = t * 7 + i;
    const int c = (cid < NCELL) ? cellcnt[b * NCELL + cid] : 0;
    local[i] = c; s += c;
  }
  ps[t] = s; __syncthreads();
  for (int off = 1; off < 256; off <<= 1) {
    int v = (t >= off) ? ps[t - off] : 0;
    __syncthreads();
    ps[t] += v;
    __syncthreads();
  }
  int run = ps[t] - s;
  #pragma unroll
  for (int i = 0; i < 7; i++) {
    const int cid = t * 7 + i;
    if (cid < NCELL) { cellstart[b * 1729 + cid] = run; run += local[i]; }
  }
  if (t == 255) cellstart[b * 1729 + NCELL] = ps[255];
}

// ---------------------------------------------------------------------------
// K0c: counting-sort scatter -> qorder + sorted xyz + sorted bf16 feats
// ---------------------------------------------------------------------------
__global__ __launch_bounds__(256) void k0c_scatter(
    const float* __restrict__ xyz, const float* __restrict__ feats,
    const int* __restrict__ cellstart, int* __restrict__ cellfill,
    int* __restrict__ qorder, float4* __restrict__ xyzs,
    unsigned short* __restrict__ fsorted)
{
  const int pt = blockIdx.x * 256 + threadIdx.x;
  const float x = xyz[pt * 3], y = xyz[pt * 3 + 1], z = xyz[pt * 3 + 2];
  const int b = pt >> 12;
  const int cid = cell_of(x, y, z);
  const int slot = atomicAdd(&cellfill[b * NCELL + cid], 1);
  const int pos = b * NPTS + cellstart[b * 1729 + cid] + slot;
  qorder[pos] = pt;
  xyzs[pos] = make_float4(x, y, z, 0.f);
  const float* src = &feats[(size_t)pt * CIN];
  uint4* dst = (uint4*)&fsorted[(size_t)pos * CIN];
  #pragma unroll
  for (int g = 0; g < 8; g++) {
    float4 a = *(const float4*)(src + g * 8);
    float4 c = *(const float4*)(src + g * 8 + 4);
    union { unsigned short s[8]; uint4 v; } u;
    u.s[0] = f2bf(a.x); u.s[1] = f2bf(a.y); u.s[2] = f2bf(a.z); u.s[3] = f2bf(a.w);
    u.s[4] = f2bf(c.x); u.s[5] = f2bf(c.y); u.s[6] = f2bf(c.z); u.s[7] = f2bf(c.w);
    dst[g] = u.v;
  }
}

// ---------------------------------------------------------------------------
// K2: block-union MFMA KPConv.  2048 blocks x 256 thr (4 waves), 16 sorted
// queries/block, 32768 B LDS -> 5 blocks/CU.
// ---------------------------------------------------------------------------
__global__ __launch_bounds__(256, 5) void k2_conv(
    const float4* __restrict__ xyzs, const unsigned short* __restrict__ fsorted,
    const float* __restrict__ kpts, const int* __restrict__ cellstart,
    const int* __restrict__ qorder, const unsigned short* __restrict__ Wt,
    float* __restrict__ out, float* __restrict__ psum,
    float* __restrict__ psumsq)
{
  // phase-aliased LDS (32000 B):
  //   [0..6400)       Pu[400] float4    (search+stage-1)
  //   [6400..14592)   cpos[4096] ushort (prologue+search, dies before S use)
  //   [6400..26880)   S[128][40] short  (8-query half, stage-1)
  //   [26880..32000)  FT[64][40] short  (chunks)
  //   [0..30720)      wf 16 x 1920 B    (k-major, XOR-swizzled; stage-2)
  __shared__ char smraw[32000] __attribute__((aligned(16)));
  float4*         Pu   = (float4*)smraw;
  unsigned short* cpos = (unsigned short*)(smraw + 6400);
  short (*S)[SP]       = (short(*)[SP])(smraw + 6400);
  short (*FT)[SP]      = (short(*)[SP])(smraw + 26880);

  __shared__ float4 qd[16];
  __shared__ int    qm[16];
  __shared__ float  kp[NKP][4];   // (-2kx, -2ky, -2kz, |kp|^2)
  __shared__ int    Tsh;
  __shared__ int    ucnt;

  const int tid = threadIdx.x;
  const int w   = tid >> 6;
  const int L   = tid & 63;
  const int m0  = blockIdx.x * 16;
  const int b   = m0 >> 12;

  if (tid >= 64 && tid < 64 + NKP) {
    const int k = tid - 64;
    const float kx = kpts[k * 3], ky = kpts[k * 3 + 1], kz = kpts[k * 3 + 2];
    kp[k][0] = -2.f * kx; kp[k][1] = -2.f * ky; kp[k][2] = -2.f * kz;
    kp[k][3] = kx * kx + ky * ky + kz * kz;
  }

  // ---- wave-0 prologue: bbox -> row ranges -> pfx (shfl scan) -> cpos ----
  if (tid < 64) {
    int cxm = 12, cym = 12, czm = 12, cxM = -1, cyM = -1, czM = -1;
    if (tid < 16) {
      const float4 Q = xyzs[m0 + tid];
      qd[tid] = Q;
      qm[tid] = qorder[m0 + tid];
      int a = (int)(Q.x * 12.f); a = a > 11 ? 11 : a;
      int c = (int)(Q.y * 12.f); c = c > 11 ? 11 : c;
      int d = (int)(Q.z * 12.f); d = d > 11 ? 11 : d;
      cxm = cxM = a; cym = cyM = c; czm = czM = d;
    }
    #pragma unroll
    for (int off = 8; off >= 1; off >>= 1) {
      int v;
      v = __shfl_xor(cxm, off); cxm = v < cxm ? v : cxm;
      v = __shfl_xor(cxM, off); cxM = v > cxM ? v : cxM;
      v = __shfl_xor(cym, off); cym = v < cym ? v : cym;
      v = __shfl_xor(cyM, off); cyM = v > cyM ? v : cyM;
      v = __shfl_xor(czm, off); czm = v < czm ? v : czm;
      v = __shfl_xor(czM, off); czM = v > czM ? v : czM;
    }
    cxm = __shfl(cxm, 0); cxM = __shfl(cxM, 0);
    cym = __shfl(cym, 0); cyM = __shfl(cyM, 0);
    czm = __shfl(czm, 0); czM = __shfl(czM, 0);

    const int x0 = cxm > 0 ? cxm - 1 : 0, x1 = cxM < 11 ? cxM + 1 : 11;
    const int y0 = cym > 0 ? cym - 1 : 0, y1 = cyM < 11 ? cyM + 1 : 11;
    const int z0 = czm > 0 ? czm - 1 : 0, z1 = czM < 11 ? czM + 1 : 11;
    const int yspan = y1 - y0 + 1;
    int nr = yspan * (z1 - z0 + 1);
    nr = nr > 64 ? 64 : nr;

    int rs = 0, len = 0;
    if (tid < nr) {
      const int zz = z0 + tid / yspan, yy = y0 + tid % yspan;
      const int base = b * 1729 + (zz * 12 + yy) * 12;
      rs  = cellstart[base + x0];
      len = cellstart[base + x1 + 1] - rs;
    }
    int incl = len;
    #pragma unroll
    for (int off = 1; off < 64; off <<= 1) {
      const int v = __shfl_up(incl, off);
      if (tid >= off) incl += v;
    }
    const int excl = incl - len;
    for (int i = 0; i < len; i++) cpos[excl + i] = (unsigned short)(rs + i);
    if (tid == 63) Tsh = incl;
    if (tid == 62) ucnt = 0;
  }
  __syncthreads();
  const int T = Tsh;

  // ---- union search: any-hit over 16 queries, branch-free test ----
  for (int tb = 0; tb < T; tb += 256) {
    const int t = tb + tid;
    if (t < T) {
      const int pos = (int)cpos[t];
      const float4 P = xyzs[b * NPTS + pos];
      float best = 1e9f;
      #pragma unroll
      for (int i = 0; i < 16; i++) {
        const float4 Q = qd[i];
        const float dx = P.x - Q.x, dy = P.y - Q.y, dz = P.z - Q.z;
        const float d2 = dx * dx + dy * dy + dz * dz;
        best = d2 < best ? d2 : best;
      }
      if (best <= R2EFF) {
        const int slot = atomicAdd(&ucnt, 1);
        if (slot < UCAP)
          Pu[slot] = make_float4(P.x, P.y, P.z, __int_as_float(pos));
      }
    }
  }
  __syncthreads();
  int U = ucnt; U = U > UCAP ? UCAP : U;

  // ---- stage-1: chunked MFMA over the union, two 8-query half-passes ----
  const int ln = L & 15;
  const int kh = L >> 4;
  const int qh = tid >> 5;      // 0..7 local query of this half
  const int nn = tid & 31;      // chunk column

  f32x4_t acc[16];
  #pragma unroll
  for (int mt = 0; mt < 16; mt++) acc[mt] = (f32x4_t){0.f, 0.f, 0.f, 0.f};

  for (int ub = 0; ub < U; ub += 32) {
    // FT[c][i]: sorted bf16 rows (L2-hot, spatially local)
    {
      const int c  = tid & 63;
      const int i0 = tid >> 6;
      #pragma unroll
      for (int ii = 0; ii < 8; ii++) {
        const int i = ii * 4 + i0;
        const int u = ub + i;
        short v = 0;
        if (u < U) {
          const int pos = __float_as_int(Pu[u].w);
          v = (short)fsorted[(size_t)(b * NPTS + pos) * CIN + c];
        }
        FT[c][i] = v;
      }
    }

    bf16x8_t bb;   // FT fragment, reused by both halves
    #pragma unroll
    for (int half = 0; half < 2; half++) {
      // S fill: one (q, n) pair per thread for queries half*8 .. half*8+7
      {
        const int u = ub + nn;
        if (u < U) {
          const float4 P = Pu[u];
          const float4 Q = qd[half * 8 + qh];
          const float rx = P.x - Q.x, ry = P.y - Q.y, rz = P.z - Q.z;
          const float rr = rx * rx + ry * ry + rz * rz;
          #pragma unroll
          for (int k = 0; k < NKP; k++) {
            float d2 = fmaf(kp[k][0], rx,
                       fmaf(kp[k][1], ry,
                       fmaf(kp[k][2], rz, rr + kp[k][3])));
            d2 = fmaxf(d2, 0.f);
            const float wv =
                fmaxf(fmaf(-KP_INV, __builtin_amdgcn_sqrtf(d2), 1.f), 0.f);
            S[qh * 16 + k][nn] = (short)f2bf_fast(wv);
          }
          S[qh * 16 + 15][nn] = 0;
        } else {
          #pragma unroll
          for (int k = 0; k < 16; k++) S[qh * 16 + k][nn] = 0;
        }
      }
      __syncthreads();
      if (half == 0) bb = *(const bf16x8_t*)&FT[w * 16 + ln][kh * 8];
      #pragma unroll
      for (int mt = 0; mt < 8; mt++) {
        bf16x8_t aa = *(const bf16x8_t*)&S[mt * 16 + ln][kh * 8];
        acc[half * 8 + mt] =
            __builtin_amdgcn_mfma_f32_16x16x32_bf16(aa, bb, acc[half * 8 + mt],
                                                    0, 0, 0);
      }
      __syncthreads();
    }
  }

  // ---- writeback: D -> wf[q][k*64+c], XOR-swizzled (aliased region) ----
  {
    const int c = w * 16 + ln;
    #pragma unroll
    for (int mt = 0; mt < 16; mt++) {
      #pragma unroll
      for (int j = 0; j < 4; j++) {
        const int k = kh * 4 + j;
        if (k < 15) {      // kh==3,j==3 (k=15) is identically zero: dropped
          int byteo = mt * WFROW + ((k * 64 + c) << 1);
          byteo ^= (mt & 7) << 4;
          *(unsigned short*)(smraw + byteo) = f2bf_fast(acc[mt][j]);
        }
      }
    }
  }
  __syncthreads();

  // ---- stage-2: out[16][128] = wf[16][960] @ Wt^T ----
  const int colbase = w * 32;

  f32x4_t acc2[2];
  acc2[0] = (f32x4_t){0.f, 0.f, 0.f, 0.f};
  acc2[1] = (f32x4_t){0.f, 0.f, 0.f, 0.f};

  const unsigned short* Bp0 = &Wt[(size_t)(colbase + ln) * KCP + kh * 8];
  const unsigned short* Bp1 = Bp0 + 16 * KCP;
  const char* wfb = (const char*)smraw + ln * WFROW;
  const int   sw  = (ln & 7) << 4;

  #pragma unroll 6
  for (int kk = 0; kk < 30; kk++) {
    const int ko  = kk * 32;
    const int inr = (kh * 16 + kk * 64) ^ sw;
    bf16x8_t b0 = *(const bf16x8_t*)(Bp0 + ko);
    bf16x8_t b1 = *(const bf16x8_t*)(Bp1 + ko);
    bf16x8_t a0 = *(const bf16x8_t*)(wfb + inr);
    acc2[0] = __builtin_amdgcn_mfma_f32_16x16x32_bf16(a0, b0, acc2[0], 0, 0, 0);
    acc2[1] = __builtin_amdgcn_mfma_f32_16x16x32_bf16(a0, b1, acc2[1], 0, 0, 0);
  }

  // BN partials: reduce 16 rows across kh via shfl, atomic into psum[128]
  float s0 = 0.f, q0 = 0.f, s1 = 0.f, q1 = 0.f;
  #pragma unroll
  for (int j = 0; j < 4; j++) {
    s0 += acc2[0][j]; q0 += acc2[0][j] * acc2[0][j];
    s1 += acc2[1][j]; q1 += acc2[1][j] * acc2[1][j];
  }
  s0 += __shfl_xor(s0, 16); s0 += __shfl_xor(s0, 32);
  q0 += __shfl_xor(q0, 16); q0 += __shfl_xor(q0, 32);
  s1 += __shfl_xor(s1, 16); s1 += __shfl_xor(s1, 32);
  q1 += __shfl_xor(q1, 16); q1 += __shfl_xor(q1, 32);
  if (kh == 0) {
    atomicAdd(&psum[colbase + ln], s0);
    atomicAdd(&psumsq[colbase + ln], q0);
    atomicAdd(&psum[colbase + 16 + ln], s1);
    atomicAdd(&psumsq[colbase + 16 + ln], q1);
  }

  // C/D layout: col = lane&15, row = (lane>>4)*4 + reg; scatter via qm[]
  #pragma unroll
  for (int c = 0; c < 2; c++) {
    #pragma unroll
    for (int j = 0; j < 4; j++) {
      const int row = kh * 4 + j;
      out[(size_t)qm[row] * COUT + colbase + c * 16 + ln] = acc2[c][j];
    }
  }
}

// ---------------------------------------------------------------------------
// K4: BN finalize (per-block, from psum) + normalize + LeakyReLU
// ---------------------------------------------------------------------------
__global__ __launch_bounds__(256) void k4_norm(
    float* __restrict__ out, const float* __restrict__ psum,
    const float* __restrict__ psumsq, const float* __restrict__ gamma,
    const float* __restrict__ beta)
{
  __shared__ float a_s[128], b_s[128];
  if (threadIdx.x < 128) {
    const int d = threadIdx.x;
    double mu  = (double)psum[d] / (double)M_TOT;
    double var = (double)psumsq[d] / (double)M_TOT - mu * mu;  // biased
    float rstd = (float)(1.0 / sqrt(var + 1e-5));
    float a = rstd * gamma[d];
    a_s[d] = a;
    b_s[d] = beta[d] - (float)mu * a;
  }
  __syncthreads();
  const int idx = blockIdx.x * 256 + threadIdx.x;   // float4 index
  float4 v = ((const float4*)out)[idx];
  const int d0 = (idx * 4) & 127;
  float y0 = v.x * a_s[d0 + 0] + b_s[d0 + 0];
  float y1 = v.y * a_s[d0 + 1] + b_s[d0 + 1];
  float y2 = v.z * a_s[d0 + 2] + b_s[d0 + 2];
  float y3 = v.w * a_s[d0 + 3] + b_s[d0 + 3];
  v.x = y0 >= 0.f ? y0 : NEG_SLOPE * y0;
  v.y = y1 >= 0.f ? y1 : NEG_SLOPE * y1;
  v.z = y2 >= 0.f ? y2 : NEG_SLOPE * y2;
  v.w = y3 >= 0.f ? y3 : NEG_SLOPE * y3;
  ((float4*)out)[idx] = v;
}

// ---------------------------------------------------------------------------
extern "C" void kernel_launch(void* const* d_in, const int* in_sizes, int n_in,
                              void* d_out, int out_size, void* d_ws,
                              size_t ws_size, hipStream_t stream)
{
  const float* xyz   = (const float*)d_in[0];
  const float* feats = (const float*)d_in[1];
  const float* kpts  = (const float*)d_in[2];
  const float* W     = (const float*)d_in[3];
  const float* gamma = (const float*)d_in[4];
  const float* beta  = (const float*)d_in[5];
  float* out = (float*)d_out;

  char* ws = (char*)d_ws;
  int*            cellcnt   = (int*)(ws + 0);           //  55296 B ─┐
  int*            cellfill  = (int*)(ws + 55296);       //  55296 B  │ zeroed
  float*          psum      = (float*)(ws + 110592);    //    512 B  │
  float*          psumsq    = (float*)(ws + 111104);    //    512 B ─┘
  int*            cellstart = (int*)(ws + 111616);      //  55424 B
  int*            qorder    = (int*)(ws + 167040);      // 131072 B
  float4*         xyzs      = (float4*)(ws + 298112);   // 524288 B
  unsigned short* fsorted   = (unsigned short*)(ws + 822400);   // 4194304 B
  unsigned short* Wt        = (unsigned short*)(ws + 5016704);  // 245760 B

  hipMemsetAsync(ws, 0, 111616, stream);

  k0a_hist   <<< 128, 256, 0, stream>>>(xyz, cellcnt);
  k0b_scan_kW<<<  40, 256, 0, stream>>>(cellcnt, cellstart, W, Wt);
  k0c_scatter<<< 128, 256, 0, stream>>>(xyz, feats, cellstart, cellfill,
                                        qorder, xyzs, fsorted);
  k2_conv    <<<2048, 256, 0, stream>>>(xyzs, fsorted, kpts, cellstart,
                                        qorder, Wt, out, psum, psumsq);
  k4_norm    <<<(out_size / 4) / 256, 256, 0, stream>>>(out, psum, psumsq,
                                                        gamma, beta);
}

// Round 3
// 194.907 us; speedup vs baseline: 1.0120x; 1.0052x over previous
//
#include <hip/hip_runtime.h>

// KPConv simple block: grid + block-union MFMA KPConv + BN + LeakyReLU
// B=8, N=4096 -> M=32768; C_IN=64, C_OUT=128, K=15 kernel pts.
//
// Exact simplification: influence w = max(1 - d/0.04, 0) with ||kp||<=0.042
// => candidates with ||rel|| >= 0.082 contribute 0 to every kernel point;
// the within-0.082 set == reference top-k result.
//
// R15 = R14 with three latency attacks on k2 (stall-bound: 22% VALU + 5%
// MFMA issue, ~70% wait):
//  (1) XCD-chunked tile swizzle: tile=(bid&7)*256+bid>>3 -> XCD x works
//      batch x only; gather set (512KB fsorted + 64KB xyzs) L2-resident.
//  (2) FT register-prefetch (async-stage split): next chunk's coalesced
//      fsorted gathers issued under current chunk's S-fill+MFMA.
//  (3) wave-ballot union compaction: 1 shared atomic per wave per pass
//      (was 1 per hit).

#define NB     8
#define NPTS   4096
#define M_TOT  32768
#define CIN    64
#define COUT   128
#define NKP    15
#define NCELL  1728            // 12^3
#define UCAP   400             // union cap (mean ~70)
#define R2EFF  (0.082f * 0.082f)
#define KP_INV 25.0f           // 1 / KP_EXTENT(0.04)
#define NEG_SLOPE 0.2f
#define KCP    960             // kc' = k*64+c, k-major, k=15 dropped
#define WFROW  1920            // wf row stride bytes (960 bf16)
#define SP     40              // S/FT row stride (shorts), 80B

typedef float f32x4_t __attribute__((ext_vector_type(4)));
typedef short bf16x8_t __attribute__((ext_vector_type(8)));

__device__ __forceinline__ unsigned short f2bf(float f) {
  union { float f; unsigned u; } v; v.f = f;
  unsigned r = v.u + 0x7FFF + ((v.u >> 16) & 1);   // RNE
  return (unsigned short)(r >> 16);
}
// half-up rounding: same 0.5 ulp max error as RNE, 2 VALU ops
__device__ __forceinline__ unsigned short f2bf_fast(float f) {
  union { float f; unsigned u; } v; v.f = f;
  return (unsigned short)((v.u + 0x8000u) >> 16);
}
__device__ __forceinline__ int cell_of(float x, float y, float z) {
  int cx = (int)(x * 12.f); cx = cx > 11 ? 11 : cx;
  int cy = (int)(y * 12.f); cy = cy > 11 ? 11 : cy;
  int cz = (int)(z * 12.f); cz = cz > 11 ? 11 : cz;
  return (cz * 12 + cy) * 12 + cx;
}

// ---------------------------------------------------------------------------
// K0a: per-cell histogram
// ---------------------------------------------------------------------------
__global__ __launch_bounds__(256) void k0a_hist(
    const float* __restrict__ xyz, int* __restrict__ cellcnt)
{
  const int pt = blockIdx.x * 256 + threadIdx.x;
  const float x = xyz[pt * 3], y = xyz[pt * 3 + 1], z = xyz[pt * 3 + 2];
  const int b = pt >> 12;
  atomicAdd(&cellcnt[b * NCELL + cell_of(x, y, z)], 1);
}

// ---------------------------------------------------------------------------
// K0b: blocks 0..7 = per-batch exclusive scan; blocks 8..39 = W -> Wt
// Wt[d][k*64+c] bf16, k-major, k=15 dropped (its S rows are zero anyway).
// ---------------------------------------------------------------------------
__global__ __launch_bounds__(256) void k0b_scan_kW(
    const int* __restrict__ cellcnt, int* __restrict__ cellstart,
    const float* __restrict__ W, unsigned short* __restrict__ Wt)
{
  if (blockIdx.x >= 8) {
    const int idx = (blockIdx.x - 8) * 256 + threadIdx.x;  // 8192
    const int c = idx & 63, d = idx >> 6;                  // d 0..127
    #pragma unroll
    for (int k = 0; k < NKP; k++)
      Wt[(size_t)d * KCP + k * 64 + c] =
          f2bf(W[(size_t)k * (CIN * COUT) + c * COUT + d]);
    return;
  }
  __shared__ int ps[256];
  const int b = blockIdx.x, t = threadIdx.x;
  int local[7], s = 0;
  #pragma unroll
  for (int i = 0; i < 7; i++) {
    const int cid = t * 7 + i;
    const int c = (cid < NCELL) ? cellcnt[b * NCELL + cid] : 0;
    local[i] = c; s += c;
  }
  ps[t] = s; __syncthreads();
  for (int off = 1; off < 256; off <<= 1) {
    int v = (t >= off) ? ps[t - off] : 0;
    __syncthreads();
    ps[t] += v;
    __syncthreads();
  }
  int run = ps[t] - s;
  #pragma unroll
  for (int i = 0; i < 7; i++) {
    const int cid = t * 7 + i;
    if (cid < NCELL) { cellstart[b * 1729 + cid] = run; run += local[i]; }
  }
  if (t == 255) cellstart[b * 1729 + NCELL] = ps[255];
}

// ---------------------------------------------------------------------------
// K0c: counting-sort scatter -> qorder + sorted xyz + sorted bf16 feats
// ---------------------------------------------------------------------------
__global__ __launch_bounds__(256) void k0c_scatter(
    const float* __restrict__ xyz, const float* __restrict__ feats,
    const int* __restrict__ cellstart, int* __restrict__ cellfill,
    int* __restrict__ qorder, float4* __restrict__ xyzs,
    unsigned short* __restrict__ fsorted)
{
  const int pt = blockIdx.x * 256 + threadIdx.x;
  const float x = xyz[pt * 3], y = xyz[pt * 3 + 1], z = xyz[pt * 3 + 2];
  const int b = pt >> 12;
  const int cid = cell_of(x, y, z);
  const int slot = atomicAdd(&cellfill[b * NCELL + cid], 1);
  const int pos = b * NPTS + cellstart[b * 1729 + cid] + slot;
  qorder[pos] = pt;
  xyzs[pos] = make_float4(x, y, z, 0.f);
  const float* src = &feats[(size_t)pt * CIN];
  uint4* dst = (uint4*)&fsorted[(size_t)pos * CIN];
  #pragma unroll
  for (int g = 0; g < 8; g++) {
    float4 a = *(const float4*)(src + g * 8);
    float4 c = *(const float4*)(src + g * 8 + 4);
    union { unsigned short s[8]; uint4 v; } u;
    u.s[0] = f2bf(a.x); u.s[1] = f2bf(a.y); u.s[2] = f2bf(a.z); u.s[3] = f2bf(a.w);
    u.s[4] = f2bf(c.x); u.s[5] = f2bf(c.y); u.s[6] = f2bf(c.z); u.s[7] = f2bf(c.w);
    dst[g] = u.v;
  }
}

// ---------------------------------------------------------------------------
// K2: block-union MFMA KPConv.  2048 blocks x 256 thr (4 waves), 16 sorted
// queries/block, 32768 B LDS -> 5 blocks/CU.
// ---------------------------------------------------------------------------
__global__ __launch_bounds__(256, 5) void k2_conv(
    const float4* __restrict__ xyzs, const unsigned short* __restrict__ fsorted,
    const float* __restrict__ kpts, const int* __restrict__ cellstart,
    const int* __restrict__ qorder, const unsigned short* __restrict__ Wt,
    float* __restrict__ out, float* __restrict__ psum,
    float* __restrict__ psumsq)
{
  // phase-aliased LDS (32000 B):
  //   [0..6400)       Pu[400] float4    (search+stage-1)
  //   [6400..14592)   cpos[4096] ushort (prologue+search, dies before S use)
  //   [6400..26880)   S[128][40] short  (8-query half, stage-1)
  //   [26880..32000)  FT[64][40] short  (chunks)
  //   [0..30720)      wf 16 x 1920 B    (k-major, XOR-swizzled; stage-2)
  __shared__ char smraw[32000] __attribute__((aligned(16)));
  float4*         Pu   = (float4*)smraw;
  unsigned short* cpos = (unsigned short*)(smraw + 6400);
  short (*S)[SP]       = (short(*)[SP])(smraw + 6400);
  short (*FT)[SP]      = (short(*)[SP])(smraw + 26880);

  __shared__ float4 qd[16];
  __shared__ int    qm[16];
  __shared__ float  kp[NKP][4];   // (-2kx, -2ky, -2kz, |kp|^2)
  __shared__ int    Tsh;
  __shared__ int    ucnt;

  const int tid = threadIdx.x;
  const int w   = tid >> 6;
  const int L   = tid & 63;
  // XCD-chunked swizzle: XCD x (= bid%8) owns tiles [x*256, x*256+256)
  // == batch x exactly -> per-XCD gather set (512KB fsorted + 64KB xyzs)
  // is L2-resident; zero cross-XCD re-fetch of gather data.
  const int tile = ((blockIdx.x & 7) << 8) | (blockIdx.x >> 3);
  const int m0  = tile * 16;
  const int b   = m0 >> 12;

  if (tid >= 64 && tid < 64 + NKP) {
    const int k = tid - 64;
    const float kx = kpts[k * 3], ky = kpts[k * 3 + 1], kz = kpts[k * 3 + 2];
    kp[k][0] = -2.f * kx; kp[k][1] = -2.f * ky; kp[k][2] = -2.f * kz;
    kp[k][3] = kx * kx + ky * ky + kz * kz;
  }

  // ---- wave-0 prologue: bbox -> row ranges -> pfx (shfl scan) -> cpos ----
  if (tid < 64) {
    int cxm = 12, cym = 12, czm = 12, cxM = -1, cyM = -1, czM = -1;
    if (tid < 16) {
      const float4 Q = xyzs[m0 + tid];
      qd[tid] = Q;
      qm[tid] = qorder[m0 + tid];
      int a = (int)(Q.x * 12.f); a = a > 11 ? 11 : a;
      int c = (int)(Q.y * 12.f); c = c > 11 ? 11 : c;
      int d = (int)(Q.z * 12.f); d = d > 11 ? 11 : d;
      cxm = cxM = a; cym = cyM = c; czm = czM = d;
    }
    #pragma unroll
    for (int off = 8; off >= 1; off >>= 1) {
      int v;
      v = __shfl_xor(cxm, off); cxm = v < cxm ? v : cxm;
      v = __shfl_xor(cxM, off); cxM = v > cxM ? v : cxM;
      v = __shfl_xor(cym, off); cym = v < cym ? v : cym;
      v = __shfl_xor(cyM, off); cyM = v > cyM ? v : cyM;
      v = __shfl_xor(czm, off); czm = v < czm ? v : czm;
      v = __shfl_xor(czM, off); czM = v > czM ? v : czM;
    }
    cxm = __shfl(cxm, 0); cxM = __shfl(cxM, 0);
    cym = __shfl(cym, 0); cyM = __shfl(cyM, 0);
    czm = __shfl(czm, 0); czM = __shfl(czM, 0);

    const int x0 = cxm > 0 ? cxm - 1 : 0, x1 = cxM < 11 ? cxM + 1 : 11;
    const int y0 = cym > 0 ? cym - 1 : 0, y1 = cyM < 11 ? cyM + 1 : 11;
    const int z0 = czm > 0 ? czm - 1 : 0, z1 = czM < 11 ? czM + 1 : 11;
    const int yspan = y1 - y0 + 1;
    int nr = yspan * (z1 - z0 + 1);
    nr = nr > 64 ? 64 : nr;

    int rs = 0, len = 0;
    if (tid < nr) {
      const int zz = z0 + tid / yspan, yy = y0 + tid % yspan;
      const int base = b * 1729 + (zz * 12 + yy) * 12;
      rs  = cellstart[base + x0];
      len = cellstart[base + x1 + 1] - rs;
    }
    int incl = len;
    #pragma unroll
    for (int off = 1; off < 64; off <<= 1) {
      const int v = __shfl_up(incl, off);
      if (tid >= off) incl += v;
    }
    const int excl = incl - len;
    for (int i = 0; i < len; i++) cpos[excl + i] = (unsigned short)(rs + i);
    if (tid == 63) Tsh = incl;
    if (tid == 62) ucnt = 0;
  }
  __syncthreads();
  const int T = Tsh;

  // ---- union search: any-hit, wave-ballot compaction (1 atomic/wave) ----
  for (int tb = 0; tb < T; tb += 256) {
    const int t = tb + tid;
    bool hit = false;
    float4 P;
    int pos = 0;
    if (t < T) {
      pos = (int)cpos[t];
      P = xyzs[b * NPTS + pos];
      float best = 1e9f;
      #pragma unroll
      for (int i = 0; i < 16; i++) {
        const float4 Q = qd[i];
        const float dx = P.x - Q.x, dy = P.y - Q.y, dz = P.z - Q.z;
        const float d2 = dx * dx + dy * dy + dz * dz;
        best = d2 < best ? d2 : best;
      }
      hit = best <= R2EFF;
    }
    const unsigned long long m = __ballot(hit);
    if (m) {
      const int cnt = __popcll(m);
      const int leader = __ffsll((long long)m) - 1;
      int base = 0;
      if (L == leader) base = atomicAdd(&ucnt, cnt);
      base = __shfl(base, leader);
      if (hit) {
        const int slot = base + __popcll(m & ((1ull << L) - 1ull));
        if (slot < UCAP)
          Pu[slot] = make_float4(P.x, P.y, P.z, __int_as_float(pos));
      }
    }
  }
  __syncthreads();
  int U = ucnt; U = U > UCAP ? UCAP : U;

  // ---- stage-1: chunked MFMA over the union, two 8-query half-passes ----
  const int ln = L & 15;
  const int kh = L >> 4;
  const int qh = tid >> 5;      // 0..7 local query of this half
  const int nn = tid & 31;      // chunk column
  const int gc  = tid & 63;     // FT gather: channel
  const int gi0 = tid >> 6;     // FT gather: row subgroup

  f32x4_t acc[16];
  #pragma unroll
  for (int mt = 0; mt < 16; mt++) acc[mt] = (f32x4_t){0.f, 0.f, 0.f, 0.f};

  // prefetch chunk 0's FT rows into registers (coalesced 128B/wave-row)
  short pv[8];
  #pragma unroll
  for (int ii = 0; ii < 8; ii++) {
    const int u = ii * 4 + gi0;
    short v = 0;
    if (u < U) {
      const int pos = __float_as_int(Pu[u].w);
      v = (short)fsorted[(size_t)(b * NPTS + pos) * CIN + gc];
    }
    pv[ii] = v;
  }

  for (int ub = 0; ub < U; ub += 32) {
    // FT[c][i] <- prefetched registers (no exposed gather latency)
    #pragma unroll
    for (int ii = 0; ii < 8; ii++) FT[gc][ii * 4 + gi0] = pv[ii];

    // issue next chunk's gathers; latency hides under S-fill + MFMA
    const int ubn = ub + 32;
    if (ubn < U) {
      #pragma unroll
      for (int ii = 0; ii < 8; ii++) {
        const int u = ubn + ii * 4 + gi0;
        short v = 0;
        if (u < U) {
          const int pos = __float_as_int(Pu[u].w);
          v = (short)fsorted[(size_t)(b * NPTS + pos) * CIN + gc];
        }
        pv[ii] = v;
      }
    }

    bf16x8_t bb;   // FT fragment, reused by both halves
    #pragma unroll
    for (int half = 0; half < 2; half++) {
      // S fill: one (q, n) pair per thread for queries half*8 .. half*8+7
      {
        const int u = ub + nn;
        if (u < U) {
          const float4 P = Pu[u];
          const float4 Q = qd[half * 8 + qh];
          const float rx = P.x - Q.x, ry = P.y - Q.y, rz = P.z - Q.z;
          const float rr = rx * rx + ry * ry + rz * rz;
          #pragma unroll
          for (int k = 0; k < NKP; k++) {
            float d2 = fmaf(kp[k][0], rx,
                       fmaf(kp[k][1], ry,
                       fmaf(kp[k][2], rz, rr + kp[k][3])));
            d2 = fmaxf(d2, 0.f);
            const float wv =
                fmaxf(fmaf(-KP_INV, __builtin_amdgcn_sqrtf(d2), 1.f), 0.f);
            S[qh * 16 + k][nn] = (short)f2bf_fast(wv);
          }
          S[qh * 16 + 15][nn] = 0;
        } else {
          #pragma unroll
          for (int k = 0; k < 16; k++) S[qh * 16 + k][nn] = 0;
        }
      }
      __syncthreads();
      if (half == 0) bb = *(const bf16x8_t*)&FT[w * 16 + ln][kh * 8];
      #pragma unroll
      for (int mt = 0; mt < 8; mt++) {
        bf16x8_t aa = *(const bf16x8_t*)&S[mt * 16 + ln][kh * 8];
        acc[half * 8 + mt] =
            __builtin_amdgcn_mfma_f32_16x16x32_bf16(aa, bb, acc[half * 8 + mt],
                                                    0, 0, 0);
      }
      __syncthreads();
    }
  }

  // ---- writeback: D -> wf[q][k*64+c], XOR-swizzled (aliased region) ----
  {
    const int c = w * 16 + ln;
    #pragma unroll
    for (int mt = 0; mt < 16; mt++) {
      #pragma unroll
      for (int j = 0; j < 4; j++) {
        const int k = kh * 4 + j;
        if (k < 15) {      // kh==3,j==3 (k=15) is identically zero: dropped
          int byteo = mt * WFROW + ((k * 64 + c) << 1);
          byteo ^= (mt & 7) << 4;
          *(unsigned short*)(smraw + byteo) = f2bf_fast(acc[mt][j]);
        }
      }
    }
  }
  __syncthreads();

  // ---- stage-2: out[16][128] = wf[16][960] @ Wt^T ----
  const int colbase = w * 32;

  f32x4_t acc2[2];
  acc2[0] = (f32x4_t){0.f, 0.f, 0.f, 0.f};
  acc2[1] = (f32x4_t){0.f, 0.f, 0.f, 0.f};

  const unsigned short* Bp0 = &Wt[(size_t)(colbase + ln) * KCP + kh * 8];
  const unsigned short* Bp1 = Bp0 + 16 * KCP;
  const char* wfb = (const char*)smraw + ln * WFROW;
  const int   sw  = (ln & 7) << 4;

  #pragma unroll 6
  for (int kk = 0; kk < 30; kk++) {
    const int ko  = kk * 32;
    const int inr = (kh * 16 + kk * 64) ^ sw;
    bf16x8_t b0 = *(const bf16x8_t*)(Bp0 + ko);
    bf16x8_t b1 = *(const bf16x8_t*)(Bp1 + ko);
    bf16x8_t a0 = *(const bf16x8_t*)(wfb + inr);
    acc2[0] = __builtin_amdgcn_mfma_f32_16x16x32_bf16(a0, b0, acc2[0], 0, 0, 0);
    acc2[1] = __builtin_amdgcn_mfma_f32_16x16x32_bf16(a0, b1, acc2[1], 0, 0, 0);
  }

  // BN partials: reduce 16 rows across kh via shfl, atomic into psum[128]
  float s0 = 0.f, q0 = 0.f, s1 = 0.f, q1 = 0.f;
  #pragma unroll
  for (int j = 0; j < 4; j++) {
    s0 += acc2[0][j]; q0 += acc2[0][j] * acc2[0][j];
    s1 += acc2[1][j]; q1 += acc2[1][j] * acc2[1][j];
  }
  s0 += __shfl_xor(s0, 16); s0 += __shfl_xor(s0, 32);
  q0 += __shfl_xor(q0, 16); q0 += __shfl_xor(q0, 32);
  s1 += __shfl_xor(s1, 16); s1 += __shfl_xor(s1, 32);
  q1 += __shfl_xor(q1, 16); q1 += __shfl_xor(q1, 32);
  if (kh == 0) {
    atomicAdd(&psum[colbase + ln], s0);
    atomicAdd(&psumsq[colbase + ln], q0);
    atomicAdd(&psum[colbase + 16 + ln], s1);
    atomicAdd(&psumsq[colbase + 16 + ln], q1);
  }

  // C/D layout: col = lane&15, row = (lane>>4)*4 + reg; scatter via qm[]
  #pragma unroll
  for (int c = 0; c < 2; c++) {
    #pragma unroll
    for (int j = 0; j < 4; j++) {
      const int row = kh * 4 + j;
      out[(size_t)qm[row] * COUT + colbase + c * 16 + ln] = acc2[c][j];
    }
  }
}

// ---------------------------------------------------------------------------
// K4: BN finalize (per-block, from psum) + normalize + LeakyReLU
// ---------------------------------------------------------------------------
__global__ __launch_bounds__(256) void k4_norm(
    float* __restrict__ out, const float* __restrict__ psum,
    const float* __restrict__ psumsq, const float* __restrict__ gamma,
    const float* __restrict__ beta)
{
  __shared__ float a_s[128], b_s[128];
  if (threadIdx.x < 128) {
    const int d = threadIdx.x;
    double mu  = (double)psum[d] / (double)M_TOT;
    double var = (double)psumsq[d] / (double)M_TOT - mu * mu;  // biased
    float rstd = (float)(1.0 / sqrt(var + 1e-5));
    float a = rstd * gamma[d];
    a_s[d] = a;
    b_s[d] = beta[d] - (float)mu * a;
  }
  __syncthreads();
  const int idx = blockIdx.x * 256 + threadIdx.x;   // float4 index
  float4 v = ((const float4*)out)[idx];
  const int d0 = (idx * 4) & 127;
  float y0 = v.x * a_s[d0 + 0] + b_s[d0 + 0];
  float y1 = v.y * a_s[d0 + 1] + b_s[d0 + 1];
  float y2 = v.z * a_s[d0 + 2] + b_s[d0 + 2];
  float y3 = v.w * a_s[d0 + 3] + b_s[d0 + 3];
  v.x = y0 >= 0.f ? y0 : NEG_SLOPE * y0;
  v.y = y1 >= 0.f ? y1 : NEG_SLOPE * y1;
  v.z = y2 >= 0.f ? y2 : NEG_SLOPE * y2;
  v.w = y3 >= 0.f ? y3 : NEG_SLOPE * y3;
  ((float4*)out)[idx] = v;
}

// ---------------------------------------------------------------------------
extern "C" void kernel_launch(void* const* d_in, const int* in_sizes, int n_in,
                              void* d_out, int out_size, void* d_ws,
                              size_t ws_size, hipStream_t stream)
{
  const float* xyz   = (const float*)d_in[0];
  const float* feats = (const float*)d_in[1];
  const float* kpts  = (const float*)d_in[2];
  const float* W     = (const float*)d_in[3];
  const float* gamma = (const float*)d_in[4];
  const float* beta  = (const float*)d_in[5];
  float* out = (float*)d_out;

  char* ws = (char*)d_ws;
  int*            cellcnt   = (int*)(ws + 0);           //  55296 B ─┐
  int*            cellfill  = (int*)(ws + 55296);       //  55296 B  │ zeroed
  float*          psum      = (float*)(ws + 110592);    //    512 B  │
  float*          psumsq    = (float*)(ws + 111104);    //    512 B ─┘
  int*            cellstart = (int*)(ws + 111616);      //  55424 B
  int*            qorder    = (int*)(ws + 167040);      // 131072 B
  float4*         xyzs      = (float4*)(ws + 298112);   // 524288 B
  unsigned short* fsorted   = (unsigned short*)(ws + 822400);   // 4194304 B
  unsigned short* Wt        = (unsigned short*)(ws + 5016704);  // 245760 B

  hipMemsetAsync(ws, 0, 111616, stream);

  k0a_hist   <<< 128, 256, 0, stream>>>(xyz, cellcnt);
  k0b_scan_kW<<<  40, 256, 0, stream>>>(cellcnt, cellstart, W, Wt);
  k0c_scatter<<< 128, 256, 0, stream>>>(xyz, feats, cellstart, cellfill,
                                        qorder, xyzs, fsorted);
  k2_conv    <<<2048, 256, 0, stream>>>(xyzs, fsorted, kpts, cellstart,
                                        qorder, Wt, out, psum, psumsq);
  k4_norm    <<<(out_size / 4) / 256, 256, 0, stream>>>(out, psum, psumsq,
                                                        gamma, beta);
}